// Round 2
// baseline (3353.124 us; speedup 1.0000x reference)
//
#include <hip/hip_runtime.h>
#include <math.h>

#define NB   256
#define ND   63
#define NN   3969        // 63*63
#define MLc  3
#define KSc  7
#define MIDc 32

__device__ __forceinline__ float gelu_f(float v){
    return 0.5f * v * (1.0f + erff(v * 0.70710678118654752440f));
}

#define FMA4(A, W, S) { (A).x=fmaf((W).x,(S),(A).x); (A).y=fmaf((W).y,(S),(A).y); \
                        (A).z=fmaf((W).z,(S),(A).z); (A).w=fmaf((W).w,(S),(A).w); }

union F4 { float4 v; float a[4]; };

// ---------------- DFT tables (64x64 padded, row/col 63 zeroed) + acc reset ----
__global__ void k_tables(float* __restrict__ Fr, float* __restrict__ Fi, float* __restrict__ acc){
    int idx = blockIdx.x * blockDim.x + threadIdx.x;
    if (idx < 4096){
        int r = idx >> 6, c = idx & 63;
        float vr = 0.f, vi = 0.f;
        if (r < 63 && c < 63){
            int m = (r * c) % 63;
            float ang = 6.283185307179586f * (float)m / 63.0f;
            vr = cosf(ang); vi = -sinf(ang);
        }
        Fr[idx] = vr; Fi[idx] = vi;
    }
    if (idx == 0) acc[0] = 0.f;
}

// ---------------- weight pre-transposition: [ci][co][ky][kx] -> [tap][ci][co] -
__global__ void k_wprep(const float* __restrict__ w2, const float* __restrict__ w3,
                        const float* __restrict__ w4, const float* __restrict__ w5,
                        float* __restrict__ o2, float* __restrict__ o3,
                        float* __restrict__ o4, float* __restrict__ o5){
    int idx = blockIdx.x * blockDim.x + threadIdx.x;
    if (idx < 9216){
        int co = idx & 31, t = idx >> 5;
        int ci = t & 31, tap = t >> 5;
        int ky = tap / 3, kx = tap % 3;
        int src = ((ci*32 + co)*3 + ky)*3 + kx;
        o2[idx] = w2[src]; o3[idx] = w3[src]; o4[idx] = w4[src];
    }
    if (idx < 576){
        int co = idx & 1, t = idx >> 1;
        int ci = t & 31, tap = t >> 5;
        int ky = tap / 3, kx = tap % 3;
        int src = ((ci*2 + co)*3 + ky)*3 + kx;
        o5[idx] = w5[src];
    }
}

// ---------------- hypernet: per-sample 9->100(gelu)->147, twice --------------
__global__ void k_hyper(const float* __restrict__ kA,
                        const float* __restrict__ w1a, const float* __restrict__ b1a,
                        const float* __restrict__ w2a, const float* __restrict__ b2a,
                        const float* __restrict__ w1b, const float* __restrict__ b1b,
                        const float* __restrict__ w2b, const float* __restrict__ b2b,
                        float* __restrict__ out1, float* __restrict__ out2){
    __shared__ float a[9];
    __shared__ float hid[100];
    int b = blockIdx.x, tid = threadIdx.x;
    if (tid < 9) a[tid] = kA[b*9 + tid];
    __syncthreads();
    if (tid < 100){
        float s = b1a[tid];
        #pragma unroll
        for (int i = 0; i < 9; i++) s = fmaf(a[i], w1a[i*100 + tid], s);
        hid[tid] = gelu_f(s);
    }
    __syncthreads();
    if (tid < 147){
        float s = b2a[tid];
        for (int k = 0; k < 100; k++) s = fmaf(hid[k], w2a[k*147 + tid], s);
        out1[b*147 + tid] = s;
    }
    __syncthreads();
    if (tid < 100){
        float s = b1b[tid];
        #pragma unroll
        for (int i = 0; i < 9; i++) s = fmaf(a[i], w1b[i*100 + tid], s);
        hid[tid] = gelu_f(s);
    }
    __syncthreads();
    if (tid < 147){
        float s = b2b[tid];
        for (int k = 0; k < 100; k++) s = fmaf(hid[k], w2b[k*147 + tid], s);
        out2[b*147 + tid] = s;
    }
}

// ---------------- generic ConvTranspose2d (kept only for ct1, Cin=1) ---------
__global__ void k_ctrans(const float* __restrict__ in, const float* __restrict__ w,
                         const float* __restrict__ bias, float* __restrict__ out,
                         int Cin, int Cout, int Hin, int Hout, int stride, int pad,
                         int total, int doGelu){
    int idx = blockIdx.x * blockDim.x + threadIdx.x;
    if (idx >= total) return;
    int ox = idx % Hout; int t = idx / Hout;
    int oy = t % Hout;  t /= Hout;
    int co = t % Cout;  int b = t / Cout;
    float s = bias[co];
    for (int ky = 0; ky < 3; ky++){
        int ty = oy + pad - ky;
        if (ty < 0 || (ty % stride)) continue;
        int iy = ty / stride; if (iy >= Hin) continue;
        for (int kx = 0; kx < 3; kx++){
            int tx = ox + pad - kx;
            if (tx < 0 || (tx % stride)) continue;
            int ix = tx / stride; if (ix >= Hin) continue;
            const float* ip = in + ((size_t)b*Cin)*Hin*Hin + iy*Hin + ix;
            float acc = 0.f;
            for (int ci = 0; ci < Cin; ci++)
                acc = fmaf(ip[ci*Hin*Hin], w[((ci*Cout + co)*3 + ky)*3 + kx], acc);
            s += acc;
        }
    }
    if (doGelu) s = gelu_f(s);
    out[idx] = s;
}

// ---------------- fast ConvTranspose 32->32, stride 2, pad 1, k3, gelu -------
// Parity-class decomposition: taps are compile-time-provably in range.
// Thread unit = 4 same-parity pixels x 32 co; weights [tap][ci][co] in LDS
// (lane-uniform b128 broadcast reads), full input sample in LDS.
template<int HIN>
__global__ __launch_bounds__(256, 2) void k_ct32(const float* __restrict__ in,
                                                 const float* __restrict__ wT,
                                                 const float* __restrict__ bias,
                                                 float* __restrict__ out){
    constexpr int HOUT = 2*HIN - 1;
    constexpr int HINP = (HIN + 3) & ~3;
    constexpr int NE = (HOUT + 1) / 2, NO = HOUT / 2;
    constexpr int QE = (NE + 3) / 4, QO = (NO + 3) / 4;
    constexpr int n00 = NE*QE, n01 = NE*QO, n10 = NO*QE, n11 = NO*QO;
    constexpr int TOT = n00 + n01 + n10 + n11;
    __shared__ __align__(16) float in_s[32*HIN*HINP + 8];
    __shared__ __align__(16) float w_s[9216];
    __shared__ __align__(16) float bias_s[32];
    const int b = blockIdx.x >> 1, half = blockIdx.x & 1;
    const int tid = threadIdx.x;
    { const float4* ws4 = (const float4*)wT; float4* wd4 = (float4*)w_s;
      for (int i = tid; i < 2304; i += 256) wd4[i] = ws4[i]; }
    if (tid < 32) bias_s[tid] = bias[tid];
    { const float* gi = in + (size_t)b * (32*HIN*HIN);
      for (int i = tid; i < 32*HIN*HIN; i += 256){
        int ci = i / (HIN*HIN), rem = i % (HIN*HIN);
        int y = rem / HIN, x = rem % HIN;
        in_s[ci*(HIN*HINP) + y*HINP + x] = gi[i];
      } }
    __syncthreads();
    float* ob0 = out + (size_t)b * (32*HOUT*HOUT);
    for (int u = tid + half*256; u < TOT; u += 512){
        int a, cc, rI, q;
        if (u < n00){ a=0; cc=0; rI = u / QE; q = u % QE; }
        else if (u < n00+n01){ int v = u - n00; a=0; cc=1; rI = v / QO; q = v % QO; }
        else if (u < n00+n01+n10){ int v = u - n00 - n01; a=1; cc=0; rI = v / QE; q = v % QE; }
        else { int v = u - n00 - n01 - n10; a=1; cc=1; rI = v / QO; q = v % QO; }
        const int r = 2*rI + a;
        const int xq = q * 4;
        float4 acc[8][4];
        #pragma unroll
        for (int c4 = 0; c4 < 8; c4++){
            float4 bv = ((const float4*)bias_s)[c4];
            acc[c4][0]=bv; acc[c4][1]=bv; acc[c4][2]=bv; acc[c4][3]=bv;
        }
        int nky, kyA[2], iyA[2];
        if (a == 0){ nky=1; kyA[0]=1; iyA[0]=rI; }
        else       { nky=2; kyA[0]=0; iyA[0]=rI+1; kyA[1]=2; iyA[1]=rI; }
        int nkx, kxA[2], ixA[2];
        if (cc == 0){ nkx=1; kxA[0]=1; ixA[0]=xq; }
        else        { nkx=2; kxA[0]=0; ixA[0]=xq+1; kxA[1]=2; ixA[1]=xq; }
        for (int yi = 0; yi < nky; yi++)
        for (int xi = 0; xi < nkx; xi++){
            const int tap = kyA[yi]*3 + kxA[xi];
            const float* ip = in_s + iyA[yi]*HINP + ixA[xi];
            const float* wp = w_s + (tap << 10);
            #pragma unroll 4
            for (int ci = 0; ci < 32; ci++){
                float iv0 = ip[0], iv1 = ip[1], iv2 = ip[2], iv3 = ip[3];
                const float4* wq = (const float4*)(wp + (ci << 5));
                #pragma unroll
                for (int c4 = 0; c4 < 8; c4++){
                    float4 wv = wq[c4];
                    FMA4(acc[c4][0], wv, iv0);
                    FMA4(acc[c4][1], wv, iv1);
                    FMA4(acc[c4][2], wv, iv2);
                    FMA4(acc[c4][3], wv, iv3);
                }
                ip += HIN*HINP;
            }
        }
        int lim = (cc == 0 ? NE : NO) - xq; if (lim > 4) lim = 4;
        for (int j = 0; j < lim; j++){
            const int x = 2*(xq + j) + cc;
            float* op = ob0 + (size_t)r*HOUT + x;
            #pragma unroll
            for (int c4 = 0; c4 < 8; c4++){
                float4 v = acc[c4][j];
                op[(size_t)(c4*4+0)*HOUT*HOUT] = gelu_f(v.x);
                op[(size_t)(c4*4+1)*HOUT*HOUT] = gelu_f(v.y);
                op[(size_t)(c4*4+2)*HOUT*HOUT] = gelu_f(v.z);
                op[(size_t)(c4*4+3)*HOUT*HOUT] = gelu_f(v.w);
            }
        }
    }
}

// ---------------- ct5: 32->2, stride 2, pad 2, k3, no gelu -------------------
__global__ __launch_bounds__(256) void k_ct5(const float* __restrict__ in,
                                             const float* __restrict__ wT5,
                                             const float* __restrict__ bias,
                                             float* __restrict__ out){
    __shared__ float ws5[576];
    int tid = threadIdx.x;
    for (int i = tid; i < 576; i += 256) ws5[i] = wT5[i];
    __syncthreads();
    int idx = blockIdx.x * 256 + tid;
    if (idx >= NB*NN) return;
    int p = idx % NN, b = idx / NN;
    int oy = p / ND, ox = p % ND;
    float a0 = bias[0], a1 = bias[1];
    int nky, kyA[2], iyA[2];
    if ((oy & 1) == 0){ nky=2; kyA[0]=0; iyA[0]=oy/2+1; kyA[1]=2; iyA[1]=oy/2; }
    else              { nky=1; kyA[0]=1; iyA[0]=(oy+1)/2; }
    int nkx, kxA[2], ixA[2];
    if ((ox & 1) == 0){ nkx=2; kxA[0]=0; ixA[0]=ox/2+1; kxA[1]=2; ixA[1]=ox/2; }
    else              { nkx=1; kxA[0]=1; ixA[0]=(ox+1)/2; }
    const float* ib = in + (size_t)b * (32*33*33);
    for (int yi = 0; yi < nky; yi++)
    for (int xi = 0; xi < nkx; xi++){
        const float* ip = ib + iyA[yi]*33 + ixA[xi];
        const float* wp = ws5 + (kyA[yi]*3 + kxA[xi])*64;
        #pragma unroll 8
        for (int ci = 0; ci < 32; ci++){
            float v = ip[ci*1089];
            a0 = fmaf(v, wp[ci*2],   a0);
            a1 = fmaf(v, wp[ci*2+1], a1);
        }
    }
    out[(size_t)b*2*NN + p]      = a0;
    out[(size_t)b*2*NN + NN + p] = a1;
}

// ---------------- build spectral multiplier v (stride-64 rows) ---------------
__global__ void k_buildv(const float* __restrict__ h5, float* __restrict__ vr,
                         float* __restrict__ vi, int total){
    int idx = blockIdx.x * blockDim.x + threadIdx.x;
    if (idx >= total) return;
    int i = idx % NN; int b = idx / NN;
    int ky = i / ND, kx = i % ND;
    const float* hb = h5 + (size_t)b * 2 * NN;
    float re, im;
    if (kx <= 31){ int o = 2*i; re = hb[o]; im = hb[o+1]; }
    else {
        int sy = (ND - ky) % ND; int sx = ND - kx;
        int o = 2*(sy*ND + sx); re = hb[o]; im = -hb[o+1];
    }
    const float sc = 1.0f / 3969.0f;
    vr[(size_t)b*4032 + ky*64 + kx] = re * sc;
    vi[(size_t)b*4032 + ky*64 + kx] = im * sc;
}

// ---------------- residual: r = f - conv3x3(pad_bc(x), kA) -------------------
__global__ void k_residual(const float* __restrict__ x, const float* __restrict__ f,
                           const float* __restrict__ kA, float* __restrict__ r){
    int idx = blockIdx.x * blockDim.x + threadIdx.x;
    if (idx >= NB * NN) return;
    int i = idx % NN; int b = idx / NN;
    int y = i / ND, xx = i % ND;
    const float* ka = kA + b*9;
    const float* xb = x + (size_t)b*NN;
    float s = 0.f;
    #pragma unroll
    for (int dy = 0; dy < 3; dy++){
        int u = y + dy;
        #pragma unroll
        for (int dx = 0; dx < 3; dx++){
            int v = xx + dx;
            float p;
            if (u == 64 || v == 64)      p = 1.0f;
            else if (u == 0 || v == 0)   p = 0.0f;
            else                         p = xb[(u-1)*ND + (v-1)];
            s = fmaf(p, ka[dy*3 + dx], s);
        }
    }
    r[idx] = f[idx] - s;
}

// ---------------- fused smoother: x += conv7(conv7(residual(x),w1),w2) -------
__global__ __launch_bounds__(512) void k_smoother(const float* __restrict__ f,
                                                  const float* __restrict__ kA,
                                                  const float* __restrict__ w1,
                                                  const float* __restrict__ w2,
                                                  float* __restrict__ x){
    __shared__ float rs[63*70];
    __shared__ float tc[63*70];
    __shared__ float w1s[147], w2s[147];
    int b = blockIdx.x, tid = threadIdx.x;
    if (tid < 147){ w1s[tid] = w1[b*147 + tid]; w2s[tid] = w2[b*147 + tid]; }
    for (int i = tid; i < 63*70; i += 512){ rs[i] = 0.f; tc[i] = 0.f; }
    float* xg = x + (size_t)b*NN;
    const float* fg = f + (size_t)b*NN;
    float ka[9];
    #pragma unroll
    for (int i = 0; i < 9; i++) ka[i] = kA[b*9 + i];
    __syncthreads();
    for (int i = tid; i < NN; i += 512){
        int y = i / ND, xx = i % ND;
        float s = 0.f;
        #pragma unroll
        for (int dy = 0; dy < 3; dy++){
            int u = y + dy;
            #pragma unroll
            for (int dx = 0; dx < 3; dx++){
                int v = xx + dx;
                float p;
                if (u == 64 || v == 64)    p = 1.0f;
                else if (u == 0 || v == 0) p = 0.0f;
                else                       p = xg[(u-1)*ND + (v-1)];
                s = fmaf(p, ka[dy*3 + dx], s);
            }
        }
        rs[y*70 + 3 + xx] = fg[i] - s;
    }
    __syncthreads();
    int task = tid;
    bool active = task < 504;
    int xt = task & 7, y0 = task >> 3;
    int x0 = xt * 8;
    float acc2[8] = {0,0,0,0,0,0,0,0};
    for (int c = 0; c < 3; c++){
        if (active){
            float a1[8] = {0,0,0,0,0,0,0,0};
            for (int dy = 0; dy < 7; dy++){
                int ry = y0 + dy - 3;
                if (ry < 0 || ry >= 63) continue;
                float win[14];
                #pragma unroll
                for (int t = 0; t < 14; t++) win[t] = rs[ry*70 + x0 + t];
                #pragma unroll
                for (int dx = 0; dx < 7; dx++){
                    float wv = w1s[c*49 + dy*7 + dx];
                    #pragma unroll
                    for (int t = 0; t < 8; t++) a1[t] = fmaf(wv, win[t + dx], a1[t]);
                }
            }
            int nw = 63 - x0; if (nw > 8) nw = 8;
            for (int t = 0; t < nw; t++) tc[y0*70 + 3 + x0 + t] = a1[t];
        }
        __syncthreads();
        if (active){
            for (int dy = 0; dy < 7; dy++){
                int ry = y0 + dy - 3;
                if (ry < 0 || ry >= 63) continue;
                float win[14];
                #pragma unroll
                for (int t = 0; t < 14; t++) win[t] = tc[ry*70 + x0 + t];
                #pragma unroll
                for (int dx = 0; dx < 7; dx++){
                    float wv = w2s[c*49 + dy*7 + dx];
                    #pragma unroll
                    for (int t = 0; t < 8; t++) acc2[t] = fmaf(wv, win[t + dx], acc2[t]);
                }
            }
        }
        __syncthreads();
    }
    if (active){
        int nw = 63 - x0; if (nw > 8) nw = 8;
        float* xo = xg + y0*ND + x0;
        for (int t = 0; t < nw; t++) xo[t] += acc2[t];
    }
}

// ---------------- fused spectral correction: x += Re(F*((F r F).v)F*) --------
__global__ __launch_bounds__(256) void k_hcorrect(const float* __restrict__ Frg,
                                                  const float* __restrict__ Fig,
                                                  const float* __restrict__ r,
                                                  const float* __restrict__ vrg,
                                                  const float* __restrict__ vig,
                                                  float* __restrict__ x){
    __shared__ float sA[2*4096];
    __shared__ float sB[2*4096];
    int b = blockIdx.x, tid = threadIdx.x;
    int kt = tid >> 4, ct = tid & 15;
    int k0 = kt * 4, c0 = ct * 4;
    const float4* F4r = (const float4*)Frg;
    const float4* F4i = (const float4*)Fig;
    float4* A40 = (float4*)sA;          float4* A41 = (float4*)(sA + 4096);
    float4* B40 = (float4*)sB;          float4* B41 = (float4*)(sB + 4096);
    const float* rg = r + (size_t)b*NN;

    for (int i = tid; i < NN; i += 256) sA[(i/ND)*64 + (i%ND)] = rg[i];
    for (int i = tid; i < 64; i += 256) sA[i*64 + 63] = 0.f;
    __syncthreads();

    {
        float tr[4][4] = {}, ti[4][4] = {};
        for (int m = 0; m < 63; m++){
            F4 fr, fi, rv;
            fr.v = F4r[m*16 + kt]; fi.v = F4i[m*16 + kt];
            rv.v = A40[m*16 + ct];
            #pragma unroll
            for (int i = 0; i < 4; i++)
                #pragma unroll
                for (int j = 0; j < 4; j++){
                    tr[i][j] = fmaf(fr.a[i], rv.a[j], tr[i][j]);
                    ti[i][j] = fmaf(fi.a[i], rv.a[j], ti[i][j]);
                }
        }
        #pragma unroll
        for (int j = 0; j < 4; j++){
            F4 sv, si;
            #pragma unroll
            for (int i = 0; i < 4; i++){ sv.a[i] = tr[i][j]; si.a[i] = ti[i][j]; }
            B40[(c0 + j)*16 + kt] = sv.v;
            B41[(c0 + j)*16 + kt] = si.v;
        }
    }
    __syncthreads();

    {
        float Rr[4][4] = {}, Ri[4][4] = {};
        for (int n = 0; n < 63; n++){
            F4 ar, ai, fr, fi;
            ar.v = B40[n*16 + kt]; ai.v = B41[n*16 + kt];
            fr.v = F4r[n*16 + ct]; fi.v = F4i[n*16 + ct];
            #pragma unroll
            for (int i = 0; i < 4; i++)
                #pragma unroll
                for (int j = 0; j < 4; j++){
                    Rr[i][j] = fmaf(ar.a[i], fr.a[j], Rr[i][j]);
                    Rr[i][j] = fmaf(-ai.a[i], fi.a[j], Rr[i][j]);
                    Ri[i][j] = fmaf(ar.a[i], fi.a[j], Ri[i][j]);
                    Ri[i][j] = fmaf(ai.a[i], fr.a[j], Ri[i][j]);
                }
        }
        const float4* v4r = (const float4*)(vrg + (size_t)b*4032);
        const float4* v4i = (const float4*)(vig + (size_t)b*4032);
        #pragma unroll
        for (int i = 0; i < 4; i++){
            int k = k0 + i;
            int kk = k < 63 ? k : 62;
            F4 wr, wi, mr, mi;
            wr.v = v4r[kk*16 + ct]; wi.v = v4i[kk*16 + ct];
            #pragma unroll
            for (int j = 0; j < 4; j++){
                mr.a[j] = Rr[i][j]*wr.a[j] - Ri[i][j]*wi.a[j];
                mi.a[j] = Rr[i][j]*wi.a[j] + Ri[i][j]*wr.a[j];
            }
            A40[k*16 + ct] = mr.v;
            A41[k*16 + ct] = mi.v;
        }
    }
    __syncthreads();

    {
        float Pr[4][4] = {}, Pi[4][4] = {};
        for (int n = 0; n < 63; n++){
            F4 fr, fi, mr, mi;
            fr.v = F4r[n*16 + kt]; fi.v = F4i[n*16 + kt];
            mr.v = A40[n*16 + ct]; mi.v = A41[n*16 + ct];
            #pragma unroll
            for (int i = 0; i < 4; i++)
                #pragma unroll
                for (int j = 0; j < 4; j++){
                    Pr[i][j] = fmaf(fr.a[i], mr.a[j], Pr[i][j]);
                    Pr[i][j] = fmaf(fi.a[i], mi.a[j], Pr[i][j]);
                    Pi[i][j] = fmaf(fr.a[i], mi.a[j], Pi[i][j]);
                    Pi[i][j] = fmaf(-fi.a[i], mr.a[j], Pi[i][j]);
                }
        }
        #pragma unroll
        for (int j = 0; j < 4; j++){
            F4 sv, si;
            #pragma unroll
            for (int i = 0; i < 4; i++){ sv.a[i] = Pr[i][j]; si.a[i] = Pi[i][j]; }
            B40[(c0 + j)*16 + kt] = sv.v;
            B41[(c0 + j)*16 + kt] = si.v;
        }
    }
    __syncthreads();

    {
        float yv[4][4] = {};
        for (int l = 0; l < 63; l++){
            F4 pr, pi, fr, fi;
            pr.v = B40[l*16 + kt]; pi.v = B41[l*16 + kt];
            fr.v = F4r[l*16 + ct]; fi.v = F4i[l*16 + ct];
            #pragma unroll
            for (int i = 0; i < 4; i++)
                #pragma unroll
                for (int j = 0; j < 4; j++){
                    yv[i][j] = fmaf(pr.a[i], fr.a[j], yv[i][j]);
                    yv[i][j] = fmaf(pi.a[i], fi.a[j], yv[i][j]);
                }
        }
        float* xg = x + (size_t)b*NN;
        #pragma unroll
        for (int i = 0; i < 4; i++){
            int p = k0 + i;
            if (p < 63){
                #pragma unroll
                for (int j = 0; j < 4; j++){
                    int q = c0 + j;
                    if (q < 63) xg[p*ND + q] += yv[i][j];
                }
            }
        }
    }
}

// ---------------- norm reduction --------------------------------------------
__global__ void k_norm(const float* __restrict__ r, float* __restrict__ acc){
    float s = 0.f;
    int stride = gridDim.x * blockDim.x;
    for (int i = blockIdx.x * blockDim.x + threadIdx.x; i < NB*NN; i += stride){
        float v = r[i]; s = fmaf(v, v, s);
    }
    #pragma unroll
    for (int off = 32; off > 0; off >>= 1) s += __shfl_down(s, off, 64);
    __shared__ float red[4];
    int lane = threadIdx.x & 63, w = threadIdx.x >> 6;
    if (lane == 0) red[w] = s;
    __syncthreads();
    if (threadIdx.x == 0) atomicAdd(acc, red[0] + red[1] + red[2] + red[3]);
}

__global__ void k_final(const float* __restrict__ acc, float* __restrict__ out){
    if (threadIdx.x == 0 && blockIdx.x == 0) out[0] = sqrtf(acc[0]) * (1.0f/256.0f);
}

// ---------------- host ------------------------------------------------------
extern "C" void kernel_launch(void* const* d_in, const int* in_sizes, int n_in,
                              void* d_out, int out_size, void* d_ws, size_t ws_size,
                              hipStream_t stream){
    const float* x0     = (const float*)d_in[0];
    const float* f      = (const float*)d_in[1];
    const float* kA     = (const float*)d_in[2];
    const float* fc1_w1 = (const float*)d_in[3];
    const float* fc1_b1 = (const float*)d_in[4];
    const float* fc1_w2 = (const float*)d_in[5];
    const float* fc1_b2 = (const float*)d_in[6];
    const float* fc2_w1 = (const float*)d_in[7];
    const float* fc2_b1 = (const float*)d_in[8];
    const float* fc2_w2 = (const float*)d_in[9];
    const float* fc2_b2 = (const float*)d_in[10];
    const float* ct1_w  = (const float*)d_in[11];
    const float* ct1_b  = (const float*)d_in[12];
    const float* ct2_w  = (const float*)d_in[13];
    const float* ct2_b  = (const float*)d_in[14];
    const float* ct3_w  = (const float*)d_in[15];
    const float* ct3_b  = (const float*)d_in[16];
    const float* ct4_w  = (const float*)d_in[17];
    const float* ct4_b  = (const float*)d_in[18];
    const float* ct5_w  = (const float*)d_in[19];
    const float* ct5_b  = (const float*)d_in[20];
    float* out = (float*)d_out;

    float* ws = (float*)d_ws;
    size_t off = 0;
    auto take = [&](size_t n){ float* p = ws + off; off += (n + 63) & ~(size_t)63; return p; };
    float* Fr  = take(4096);
    float* Fi  = take(4096);
    float* acc = take(64);
    float* w1b = take((size_t)NB*147);
    float* w2b = take((size_t)NB*147);
    float* xb  = take((size_t)NB*NN);
    float* rb  = take((size_t)NB*NN);
    float* vr  = take((size_t)NB*4032);
    float* vi  = take((size_t)NB*4032);
    float* c1  = take((size_t)NB*MIDc*5*5);
    float* c2  = take((size_t)NB*MIDc*9*9);
    float* c3  = take((size_t)NB*MIDc*17*17);
    float* c4  = take((size_t)NB*MIDc*33*33);
    float* c5  = take((size_t)NB*2*NN);
    float* wT2 = take(9216);
    float* wT3 = take(9216);
    float* wT4 = take(9216);
    float* wT5 = take(576);
    (void)ws_size; (void)in_sizes; (void)n_in; (void)out_size;

    k_tables<<<16, 256, 0, stream>>>(Fr, Fi, acc);
    k_wprep<<<36, 256, 0, stream>>>(ct2_w, ct3_w, ct4_w, ct5_w, wT2, wT3, wT4, wT5);
    k_hyper<<<NB, 192, 0, stream>>>(kA, fc1_w1, fc1_b1, fc1_w2, fc1_b2,
                                    fc2_w1, fc2_b1, fc2_w2, fc2_b2, w1b, w2b);
    hipMemcpyAsync(xb, x0, (size_t)NB*NN*sizeof(float), hipMemcpyDeviceToDevice, stream);

    int t1 = NB*MIDc*5*5;
    k_ctrans<<<(t1+255)/256, 256, 0, stream>>>(kA, ct1_w, ct1_b, c1, 1, MIDc, 3, 5, 2, 1, t1, 1);
    k_ct32<5> <<<NB*2, 256, 0, stream>>>(c1, wT2, ct2_b, c2);
    k_ct32<9> <<<NB*2, 256, 0, stream>>>(c2, wT3, ct3_b, c3);
    k_ct32<17><<<NB*2, 256, 0, stream>>>(c3, wT4, ct4_b, c4);
    k_ct5<<<(NB*NN+255)/256, 256, 0, stream>>>(c4, wT5, ct5_b, c5);

    k_buildv<<<(NB*NN+255)/256, 256, 0, stream>>>(c5, vr, vi, NB*NN);

    for (int it = 0; it < 5; it++){
        k_smoother<<<NB, 512, 0, stream>>>(f, kA, w1b, w2b, xb);
        k_residual<<<(NB*NN+255)/256, 256, 0, stream>>>(xb, f, kA, rb);
        k_hcorrect<<<NB, 256, 0, stream>>>(Fr, Fi, rb, vr, vi, xb);
    }
    k_residual<<<(NB*NN+255)/256, 256, 0, stream>>>(xb, f, kA, rb);
    k_norm<<<256, 256, 0, stream>>>(rb, acc);
    k_final<<<1, 64, 0, stream>>>(acc, out);
}

// Round 3
// 673.996 us; speedup vs baseline: 4.9750x; 4.9750x over previous
//
#include <hip/hip_runtime.h>
#include <math.h>

#define NB   256
#define ND   63
#define NN   3969        // 63*63
#define MLc  3
#define KSc  7
#define MIDc 32

__device__ __forceinline__ float gelu_f(float v){
    return 0.5f * v * (1.0f + erff(v * 0.70710678118654752440f));
}

#define FMA4(A, W, S) { (A).x=fmaf((W).x,(S),(A).x); (A).y=fmaf((W).y,(S),(A).y); \
                        (A).z=fmaf((W).z,(S),(A).z); (A).w=fmaf((W).w,(S),(A).w); }

union F4 { float4 v; float a[4]; };

// ---------------- DFT tables (64x64 padded, row/col 63 zeroed) + acc reset ----
__global__ void k_tables(float* __restrict__ Fr, float* __restrict__ Fi, float* __restrict__ acc){
    int idx = blockIdx.x * blockDim.x + threadIdx.x;
    if (idx < 4096){
        int r = idx >> 6, c = idx & 63;
        float vr = 0.f, vi = 0.f;
        if (r < 63 && c < 63){
            int m = (r * c) % 63;
            float ang = 6.283185307179586f * (float)m / 63.0f;
            vr = cosf(ang); vi = -sinf(ang);
        }
        Fr[idx] = vr; Fi[idx] = vi;
    }
    if (idx == 0) acc[0] = 0.f;
}

// ---------------- weight pre-transposition: [ci][co][ky][kx] -> [tap][ci][co] -
__global__ void k_wprep(const float* __restrict__ w2, const float* __restrict__ w3,
                        const float* __restrict__ w4, const float* __restrict__ w5,
                        float* __restrict__ o2, float* __restrict__ o3,
                        float* __restrict__ o4, float* __restrict__ o5){
    int idx = blockIdx.x * blockDim.x + threadIdx.x;
    if (idx < 9216){
        int co = idx & 31, t = idx >> 5;
        int ci = t & 31, tap = t >> 5;
        int ky = tap / 3, kx = tap % 3;
        int src = ((ci*32 + co)*3 + ky)*3 + kx;
        o2[idx] = w2[src]; o3[idx] = w3[src]; o4[idx] = w4[src];
    }
    if (idx < 576){
        int co = idx & 1, t = idx >> 1;
        int ci = t & 31, tap = t >> 5;
        int ky = tap / 3, kx = tap % 3;
        int src = ((ci*2 + co)*3 + ky)*3 + kx;
        o5[idx] = w5[src];
    }
}

// ---------------- hypernet: per-sample 9->100(gelu)->147, twice --------------
__global__ void k_hyper(const float* __restrict__ kA,
                        const float* __restrict__ w1a, const float* __restrict__ b1a,
                        const float* __restrict__ w2a, const float* __restrict__ b2a,
                        const float* __restrict__ w1b, const float* __restrict__ b1b,
                        const float* __restrict__ w2b, const float* __restrict__ b2b,
                        float* __restrict__ out1, float* __restrict__ out2){
    __shared__ float a[9];
    __shared__ float hid[100];
    int b = blockIdx.x, tid = threadIdx.x;
    if (tid < 9) a[tid] = kA[b*9 + tid];
    __syncthreads();
    if (tid < 100){
        float s = b1a[tid];
        #pragma unroll
        for (int i = 0; i < 9; i++) s = fmaf(a[i], w1a[i*100 + tid], s);
        hid[tid] = gelu_f(s);
    }
    __syncthreads();
    if (tid < 147){
        float s = b2a[tid];
        for (int k = 0; k < 100; k++) s = fmaf(hid[k], w2a[k*147 + tid], s);
        out1[b*147 + tid] = s;
    }
    __syncthreads();
    if (tid < 100){
        float s = b1b[tid];
        #pragma unroll
        for (int i = 0; i < 9; i++) s = fmaf(a[i], w1b[i*100 + tid], s);
        hid[tid] = gelu_f(s);
    }
    __syncthreads();
    if (tid < 147){
        float s = b2b[tid];
        for (int k = 0; k < 100; k++) s = fmaf(hid[k], w2b[k*147 + tid], s);
        out2[b*147 + tid] = s;
    }
}

// ---------------- generic ConvTranspose2d (kept only for ct1, Cin=1) ---------
__global__ void k_ctrans(const float* __restrict__ in, const float* __restrict__ w,
                         const float* __restrict__ bias, float* __restrict__ out,
                         int Cin, int Cout, int Hin, int Hout, int stride, int pad,
                         int total, int doGelu){
    int idx = blockIdx.x * blockDim.x + threadIdx.x;
    if (idx >= total) return;
    int ox = idx % Hout; int t = idx / Hout;
    int oy = t % Hout;  t /= Hout;
    int co = t % Cout;  int b = t / Cout;
    float s = bias[co];
    for (int ky = 0; ky < 3; ky++){
        int ty = oy + pad - ky;
        if (ty < 0 || (ty % stride)) continue;
        int iy = ty / stride; if (iy >= Hin) continue;
        for (int kx = 0; kx < 3; kx++){
            int tx = ox + pad - kx;
            if (tx < 0 || (tx % stride)) continue;
            int ix = tx / stride; if (ix >= Hin) continue;
            const float* ip = in + ((size_t)b*Cin)*Hin*Hin + iy*Hin + ix;
            float acc = 0.f;
            for (int ci = 0; ci < Cin; ci++)
                acc = fmaf(ip[ci*Hin*Hin], w[((ci*Cout + co)*3 + ky)*3 + kx], acc);
            s += acc;
        }
    }
    if (doGelu) s = gelu_f(s);
    out[idx] = s;
}

// ---------------- fast ConvTranspose 32->32, stride 2, pad 1, k3, gelu -------
// Block = (sample, co-half of 16). Unit = 8 consecutive output px x 8 co
// (acc = 16 float4 = 64 VGPR). Input via 2 aligned b128 LDS reads; weights via
// 6 lane-uniform broadcast b128 reads. Odd rows (2 ky taps) first -> waves
// parity-pure. OOB input reads only feed discarded pixels (LDS padded +16).
template<int HIN>
__global__ __launch_bounds__(256) void k_ct32b(const float* __restrict__ in,
                                               const float* __restrict__ wT,
                                               const float* __restrict__ bias,
                                               float* __restrict__ out){
    constexpr int HOUT = 2*HIN - 1;
    constexpr int HINP = (HIN + 3) & ~3;
    constexpr int OCT  = (HOUT + 7) / 8;
    constexpr int UPR  = OCT * 2;              // 2 co-groups of 8
    constexpr int NODD = (HOUT/2) * UPR;
    constexpr int TOT  = HOUT * UPR;
    __shared__ __align__(16) float in_s[32*HIN*HINP + 16];
    __shared__ __align__(16) float w_s[9*32*16];     // [tap][ci][16co]
    __shared__ __align__(16) float bias_s[16];
    const int b = blockIdx.x >> 1, h = blockIdx.x & 1;
    const int tid = threadIdx.x;
    { const float4* src = (const float4*)wT;
      float4* dst = (float4*)w_s;
      for (int i = tid; i < 9*32*4; i += 256){
        int t = i >> 7, rem = i & 127;
        int ci = rem >> 2, q = rem & 3;
        dst[i] = src[t*256 + ci*8 + h*4 + q];
      } }
    if (tid < 16) bias_s[tid] = bias[h*16 + tid];
    { const float* gi = in + (size_t)b * (32*HIN*HIN);
      for (int i = tid; i < 32*HIN*HIN; i += 256){
        int ci = i / (HIN*HIN), rem = i % (HIN*HIN);
        int y = rem / HIN, x = rem % HIN;
        in_s[ci*(HIN*HINP) + y*HINP + x] = gi[i];
      } }
    __syncthreads();
    float* ob0 = out + (size_t)b*(32*HOUT*HOUT) + (size_t)(h*16)*HOUT*HOUT;
    for (int u = tid; u < TOT; u += 256){
        int r, s;
        if (u < NODD){ r = 2*(u/UPR) + 1; s = u % UPR; }
        else { int v = u - NODD; r = 2*(v/UPR); s = v % UPR; }
        const int cog = s / OCT, m = s % OCT;
        const int x4 = 4*m;
        F4 acc[8][2];
        { float4 b0 = ((const float4*)bias_s)[cog*2];
          float4 b1 = ((const float4*)bias_s)[cog*2+1];
          #pragma unroll
          for (int p = 0; p < 8; p++){ acc[p][0].v = b0; acc[p][1].v = b1; } }
        int nky, kyA[2], iyA[2];
        if (r & 1){ int rI = r >> 1; nky = 2; kyA[0]=0; iyA[0]=rI+1; kyA[1]=2; iyA[1]=rI; }
        else      { nky = 1; kyA[0]=1; iyA[0]= r >> 1; kyA[1]=1; iyA[1]=0; }
        for (int yi = 0; yi < nky; yi++){
            const float* ip = in_s + iyA[yi]*HINP + x4;
            const float* wp = w_s + kyA[yi]*3*512 + cog*8;
            #pragma unroll 2
            for (int ci = 0; ci < 32; ci++){
                F4 iv0, iv1;
                iv0.v = *(const float4*)(ip);
                iv1.v = *(const float4*)(ip + 4);
                float4 w0a = *(const float4*)(wp);
                float4 w0b = *(const float4*)(wp + 4);
                float4 w1a = *(const float4*)(wp + 512);
                float4 w1b = *(const float4*)(wp + 516);
                float4 w2a = *(const float4*)(wp + 1024);
                float4 w2b = *(const float4*)(wp + 1028);
                #pragma unroll
                for (int p = 0; p < 4; p++){
                    float ev = iv0.a[p];
                    FMA4(acc[2*p][0].v, w1a, ev);
                    FMA4(acc[2*p][1].v, w1b, ev);
                    float o0 = (p < 3) ? iv0.a[p+1] : iv1.a[0];
                    FMA4(acc[2*p+1][0].v, w0a, o0);
                    FMA4(acc[2*p+1][1].v, w0b, o0);
                    FMA4(acc[2*p+1][0].v, w2a, ev);
                    FMA4(acc[2*p+1][1].v, w2b, ev);
                }
                ip += HIN*HINP;
                wp += 16;
            }
        }
        int lim = HOUT - 8*m; if (lim > 8) lim = 8;
        float* ob = ob0 + (size_t)(cog*8)*HOUT*HOUT + (size_t)r*HOUT + 8*m;
        for (int e = 0; e < lim; e++){
            #pragma unroll
            for (int c = 0; c < 4; c++)
                ob[(size_t)c*HOUT*HOUT + e] = gelu_f(acc[e][0].a[c]);
            #pragma unroll
            for (int c = 0; c < 4; c++)
                ob[(size_t)(c+4)*HOUT*HOUT + e] = gelu_f(acc[e][1].a[c]);
        }
    }
}

// ---------------- ct5: 32->2, stride 2, pad 2, k3, no gelu -------------------
__global__ __launch_bounds__(256) void k_ct5(const float* __restrict__ in,
                                             const float* __restrict__ wT5,
                                             const float* __restrict__ bias,
                                             float* __restrict__ out){
    __shared__ float ws5[576];
    int tid = threadIdx.x;
    for (int i = tid; i < 576; i += 256) ws5[i] = wT5[i];
    __syncthreads();
    int idx = blockIdx.x * 256 + tid;
    if (idx >= NB*NN) return;
    int p = idx % NN, b = idx / NN;
    int oy = p / ND, ox = p % ND;
    float a0 = bias[0], a1 = bias[1];
    int nky, kyA[2], iyA[2];
    if ((oy & 1) == 0){ nky=2; kyA[0]=0; iyA[0]=oy/2+1; kyA[1]=2; iyA[1]=oy/2; }
    else              { nky=1; kyA[0]=1; iyA[0]=(oy+1)/2; }
    int nkx, kxA[2], ixA[2];
    if ((ox & 1) == 0){ nkx=2; kxA[0]=0; ixA[0]=ox/2+1; kxA[1]=2; ixA[1]=ox/2; }
    else              { nkx=1; kxA[0]=1; ixA[0]=(ox+1)/2; }
    const float* ib = in + (size_t)b * (32*33*33);
    for (int yi = 0; yi < nky; yi++)
    for (int xi = 0; xi < nkx; xi++){
        const float* ip = ib + iyA[yi]*33 + ixA[xi];
        const float* wp = ws5 + (kyA[yi]*3 + kxA[xi])*64;
        #pragma unroll 8
        for (int ci = 0; ci < 32; ci++){
            float v = ip[ci*1089];
            a0 = fmaf(v, wp[ci*2],   a0);
            a1 = fmaf(v, wp[ci*2+1], a1);
        }
    }
    out[(size_t)b*2*NN + p]      = a0;
    out[(size_t)b*2*NN + NN + p] = a1;
}

// ---------------- build spectral multiplier v (stride-64 rows) ---------------
__global__ void k_buildv(const float* __restrict__ h5, float* __restrict__ vr,
                         float* __restrict__ vi, int total){
    int idx = blockIdx.x * blockDim.x + threadIdx.x;
    if (idx >= total) return;
    int i = idx % NN; int b = idx / NN;
    int ky = i / ND, kx = i % ND;
    const float* hb = h5 + (size_t)b * 2 * NN;
    float re, im;
    if (kx <= 31){ int o = 2*i; re = hb[o]; im = hb[o+1]; }
    else {
        int sy = (ND - ky) % ND; int sx = ND - kx;
        int o = 2*(sy*ND + sx); re = hb[o]; im = -hb[o+1];
    }
    const float sc = 1.0f / 3969.0f;
    vr[(size_t)b*4032 + ky*64 + kx] = re * sc;
    vi[(size_t)b*4032 + ky*64 + kx] = im * sc;
}

// ---------------- residual: r = f - conv3x3(pad_bc(x), kA) -------------------
__global__ void k_residual(const float* __restrict__ x, const float* __restrict__ f,
                           const float* __restrict__ kA, float* __restrict__ r){
    int idx = blockIdx.x * blockDim.x + threadIdx.x;
    if (idx >= NB * NN) return;
    int i = idx % NN; int b = idx / NN;
    int y = i / ND, xx = i % ND;
    const float* ka = kA + b*9;
    const float* xb = x + (size_t)b*NN;
    float s = 0.f;
    #pragma unroll
    for (int dy = 0; dy < 3; dy++){
        int u = y + dy;
        #pragma unroll
        for (int dx = 0; dx < 3; dx++){
            int v = xx + dx;
            float p;
            if (u == 64 || v == 64)      p = 1.0f;
            else if (u == 0 || v == 0)   p = 0.0f;
            else                         p = xb[(u-1)*ND + (v-1)];
            s = fmaf(p, ka[dy*3 + dx], s);
        }
    }
    r[idx] = f[idx] - s;
}

// ---------------- fused smoother: x += conv7(conv7(residual(x),w1),w2) -------
__global__ __launch_bounds__(512) void k_smoother(const float* __restrict__ f,
                                                  const float* __restrict__ kA,
                                                  const float* __restrict__ w1,
                                                  const float* __restrict__ w2,
                                                  float* __restrict__ x){
    __shared__ float rs[63*70];
    __shared__ float tc[63*70];
    __shared__ float w1s[147], w2s[147];
    int b = blockIdx.x, tid = threadIdx.x;
    if (tid < 147){ w1s[tid] = w1[b*147 + tid]; w2s[tid] = w2[b*147 + tid]; }
    for (int i = tid; i < 63*70; i += 512){ rs[i] = 0.f; tc[i] = 0.f; }
    float* xg = x + (size_t)b*NN;
    const float* fg = f + (size_t)b*NN;
    float ka[9];
    #pragma unroll
    for (int i = 0; i < 9; i++) ka[i] = kA[b*9 + i];
    __syncthreads();
    for (int i = tid; i < NN; i += 512){
        int y = i / ND, xx = i % ND;
        float s = 0.f;
        #pragma unroll
        for (int dy = 0; dy < 3; dy++){
            int u = y + dy;
            #pragma unroll
            for (int dx = 0; dx < 3; dx++){
                int v = xx + dx;
                float p;
                if (u == 64 || v == 64)    p = 1.0f;
                else if (u == 0 || v == 0) p = 0.0f;
                else                       p = xg[(u-1)*ND + (v-1)];
                s = fmaf(p, ka[dy*3 + dx], s);
            }
        }
        rs[y*70 + 3 + xx] = fg[i] - s;
    }
    __syncthreads();
    int task = tid;
    bool active = task < 504;
    int xt = task & 7, y0 = task >> 3;
    int x0 = xt * 8;
    float acc2[8] = {0,0,0,0,0,0,0,0};
    for (int c = 0; c < 3; c++){
        if (active){
            float a1[8] = {0,0,0,0,0,0,0,0};
            for (int dy = 0; dy < 7; dy++){
                int ry = y0 + dy - 3;
                if (ry < 0 || ry >= 63) continue;
                float win[14];
                #pragma unroll
                for (int t = 0; t < 14; t++) win[t] = rs[ry*70 + x0 + t];
                #pragma unroll
                for (int dx = 0; dx < 7; dx++){
                    float wv = w1s[c*49 + dy*7 + dx];
                    #pragma unroll
                    for (int t = 0; t < 8; t++) a1[t] = fmaf(wv, win[t + dx], a1[t]);
                }
            }
            int nw = 63 - x0; if (nw > 8) nw = 8;
            for (int t = 0; t < nw; t++) tc[y0*70 + 3 + x0 + t] = a1[t];
        }
        __syncthreads();
        if (active){
            for (int dy = 0; dy < 7; dy++){
                int ry = y0 + dy - 3;
                if (ry < 0 || ry >= 63) continue;
                float win[14];
                #pragma unroll
                for (int t = 0; t < 14; t++) win[t] = tc[ry*70 + x0 + t];
                #pragma unroll
                for (int dx = 0; dx < 7; dx++){
                    float wv = w2s[c*49 + dy*7 + dx];
                    #pragma unroll
                    for (int t = 0; t < 8; t++) acc2[t] = fmaf(wv, win[t + dx], acc2[t]);
                }
            }
        }
        __syncthreads();
    }
    if (active){
        int nw = 63 - x0; if (nw > 8) nw = 8;
        float* xo = xg + y0*ND + x0;
        for (int t = 0; t < nw; t++) xo[t] += acc2[t];
    }
}

// ---------------- fused spectral correction: x += Re(F*((F r F).v)F*) --------
__global__ __launch_bounds__(256) void k_hcorrect(const float* __restrict__ Frg,
                                                  const float* __restrict__ Fig,
                                                  const float* __restrict__ r,
                                                  const float* __restrict__ vrg,
                                                  const float* __restrict__ vig,
                                                  float* __restrict__ x){
    __shared__ float sA[2*4096];
    __shared__ float sB[2*4096];
    int b = blockIdx.x, tid = threadIdx.x;
    int kt = tid >> 4, ct = tid & 15;
    int k0 = kt * 4, c0 = ct * 4;
    const float4* F4r = (const float4*)Frg;
    const float4* F4i = (const float4*)Fig;
    float4* A40 = (float4*)sA;          float4* A41 = (float4*)(sA + 4096);
    float4* B40 = (float4*)sB;          float4* B41 = (float4*)(sB + 4096);
    const float* rg = r + (size_t)b*NN;

    for (int i = tid; i < NN; i += 256) sA[(i/ND)*64 + (i%ND)] = rg[i];
    for (int i = tid; i < 64; i += 256) sA[i*64 + 63] = 0.f;
    __syncthreads();

    {
        float tr[4][4] = {}, ti[4][4] = {};
        for (int m = 0; m < 63; m++){
            F4 fr, fi, rv;
            fr.v = F4r[m*16 + kt]; fi.v = F4i[m*16 + kt];
            rv.v = A40[m*16 + ct];
            #pragma unroll
            for (int i = 0; i < 4; i++)
                #pragma unroll
                for (int j = 0; j < 4; j++){
                    tr[i][j] = fmaf(fr.a[i], rv.a[j], tr[i][j]);
                    ti[i][j] = fmaf(fi.a[i], rv.a[j], ti[i][j]);
                }
        }
        #pragma unroll
        for (int j = 0; j < 4; j++){
            F4 sv, si;
            #pragma unroll
            for (int i = 0; i < 4; i++){ sv.a[i] = tr[i][j]; si.a[i] = ti[i][j]; }
            B40[(c0 + j)*16 + kt] = sv.v;
            B41[(c0 + j)*16 + kt] = si.v;
        }
    }
    __syncthreads();

    {
        float Rr[4][4] = {}, Ri[4][4] = {};
        for (int n = 0; n < 63; n++){
            F4 ar, ai, fr, fi;
            ar.v = B40[n*16 + kt]; ai.v = B41[n*16 + kt];
            fr.v = F4r[n*16 + ct]; fi.v = F4i[n*16 + ct];
            #pragma unroll
            for (int i = 0; i < 4; i++)
                #pragma unroll
                for (int j = 0; j < 4; j++){
                    Rr[i][j] = fmaf(ar.a[i], fr.a[j], Rr[i][j]);
                    Rr[i][j] = fmaf(-ai.a[i], fi.a[j], Rr[i][j]);
                    Ri[i][j] = fmaf(ar.a[i], fi.a[j], Ri[i][j]);
                    Ri[i][j] = fmaf(ai.a[i], fr.a[j], Ri[i][j]);
                }
        }
        const float4* v4r = (const float4*)(vrg + (size_t)b*4032);
        const float4* v4i = (const float4*)(vig + (size_t)b*4032);
        #pragma unroll
        for (int i = 0; i < 4; i++){
            int k = k0 + i;
            int kk = k < 63 ? k : 62;
            F4 wr, wi, mr, mi;
            wr.v = v4r[kk*16 + ct]; wi.v = v4i[kk*16 + ct];
            #pragma unroll
            for (int j = 0; j < 4; j++){
                mr.a[j] = Rr[i][j]*wr.a[j] - Ri[i][j]*wi.a[j];
                mi.a[j] = Rr[i][j]*wi.a[j] + Ri[i][j]*wr.a[j];
            }
            A40[k*16 + ct] = mr.v;
            A41[k*16 + ct] = mi.v;
        }
    }
    __syncthreads();

    {
        float Pr[4][4] = {}, Pi[4][4] = {};
        for (int n = 0; n < 63; n++){
            F4 fr, fi, mr, mi;
            fr.v = F4r[n*16 + kt]; fi.v = F4i[n*16 + kt];
            mr.v = A40[n*16 + ct]; mi.v = A41[n*16 + ct];
            #pragma unroll
            for (int i = 0; i < 4; i++)
                #pragma unroll
                for (int j = 0; j < 4; j++){
                    Pr[i][j] = fmaf(fr.a[i], mr.a[j], Pr[i][j]);
                    Pr[i][j] = fmaf(fi.a[i], mi.a[j], Pr[i][j]);
                    Pi[i][j] = fmaf(fr.a[i], mi.a[j], Pi[i][j]);
                    Pi[i][j] = fmaf(-fi.a[i], mr.a[j], Pi[i][j]);
                }
        }
        #pragma unroll
        for (int j = 0; j < 4; j++){
            F4 sv, si;
            #pragma unroll
            for (int i = 0; i < 4; i++){ sv.a[i] = Pr[i][j]; si.a[i] = Pi[i][j]; }
            B40[(c0 + j)*16 + kt] = sv.v;
            B41[(c0 + j)*16 + kt] = si.v;
        }
    }
    __syncthreads();

    {
        float yv[4][4] = {};
        for (int l = 0; l < 63; l++){
            F4 pr, pi, fr, fi;
            pr.v = B40[l*16 + kt]; pi.v = B41[l*16 + kt];
            fr.v = F4r[l*16 + ct]; fi.v = F4i[l*16 + ct];
            #pragma unroll
            for (int i = 0; i < 4; i++)
                #pragma unroll
                for (int j = 0; j < 4; j++){
                    yv[i][j] = fmaf(pr.a[i], fr.a[j], yv[i][j]);
                    yv[i][j] = fmaf(pi.a[i], fi.a[j], yv[i][j]);
                }
        }
        float* xg = x + (size_t)b*NN;
        #pragma unroll
        for (int i = 0; i < 4; i++){
            int p = k0 + i;
            if (p < 63){
                #pragma unroll
                for (int j = 0; j < 4; j++){
                    int q = c0 + j;
                    if (q < 63) xg[p*ND + q] += yv[i][j];
                }
            }
        }
    }
}

// ---------------- norm reduction --------------------------------------------
__global__ void k_norm(const float* __restrict__ r, float* __restrict__ acc){
    float s = 0.f;
    int stride = gridDim.x * blockDim.x;
    for (int i = blockIdx.x * blockDim.x + threadIdx.x; i < NB*NN; i += stride){
        float v = r[i]; s = fmaf(v, v, s);
    }
    #pragma unroll
    for (int off = 32; off > 0; off >>= 1) s += __shfl_down(s, off, 64);
    __shared__ float red[4];
    int lane = threadIdx.x & 63, w = threadIdx.x >> 6;
    if (lane == 0) red[w] = s;
    __syncthreads();
    if (threadIdx.x == 0) atomicAdd(acc, red[0] + red[1] + red[2] + red[3]);
}

__global__ void k_final(const float* __restrict__ acc, float* __restrict__ out){
    if (threadIdx.x == 0 && blockIdx.x == 0) out[0] = sqrtf(acc[0]) * (1.0f/256.0f);
}

// ---------------- host ------------------------------------------------------
extern "C" void kernel_launch(void* const* d_in, const int* in_sizes, int n_in,
                              void* d_out, int out_size, void* d_ws, size_t ws_size,
                              hipStream_t stream){
    const float* x0     = (const float*)d_in[0];
    const float* f      = (const float*)d_in[1];
    const float* kA     = (const float*)d_in[2];
    const float* fc1_w1 = (const float*)d_in[3];
    const float* fc1_b1 = (const float*)d_in[4];
    const float* fc1_w2 = (const float*)d_in[5];
    const float* fc1_b2 = (const float*)d_in[6];
    const float* fc2_w1 = (const float*)d_in[7];
    const float* fc2_b1 = (const float*)d_in[8];
    const float* fc2_w2 = (const float*)d_in[9];
    const float* fc2_b2 = (const float*)d_in[10];
    const float* ct1_w  = (const float*)d_in[11];
    const float* ct1_b  = (const float*)d_in[12];
    const float* ct2_w  = (const float*)d_in[13];
    const float* ct2_b  = (const float*)d_in[14];
    const float* ct3_w  = (const float*)d_in[15];
    const float* ct3_b  = (const float*)d_in[16];
    const float* ct4_w  = (const float*)d_in[17];
    const float* ct4_b  = (const float*)d_in[18];
    const float* ct5_w  = (const float*)d_in[19];
    const float* ct5_b  = (const float*)d_in[20];
    float* out = (float*)d_out;

    float* ws = (float*)d_ws;
    size_t off = 0;
    auto take = [&](size_t n){ float* p = ws + off; off += (n + 63) & ~(size_t)63; return p; };
    float* Fr  = take(4096);
    float* Fi  = take(4096);
    float* acc = take(64);
    float* w1b = take((size_t)NB*147);
    float* w2b = take((size_t)NB*147);
    float* xb  = take((size_t)NB*NN);
    float* rb  = take((size_t)NB*NN);
    float* vr  = take((size_t)NB*4032);
    float* vi  = take((size_t)NB*4032);
    float* c1  = take((size_t)NB*MIDc*5*5);
    float* c2  = take((size_t)NB*MIDc*9*9);
    float* c3  = take((size_t)NB*MIDc*17*17);
    float* c4  = take((size_t)NB*MIDc*33*33);
    float* c5  = take((size_t)NB*2*NN);
    float* wT2 = take(9216);
    float* wT3 = take(9216);
    float* wT4 = take(9216);
    float* wT5 = take(576);
    (void)ws_size; (void)in_sizes; (void)n_in; (void)out_size;

    k_tables<<<16, 256, 0, stream>>>(Fr, Fi, acc);
    k_wprep<<<36, 256, 0, stream>>>(ct2_w, ct3_w, ct4_w, ct5_w, wT2, wT3, wT4, wT5);
    k_hyper<<<NB, 192, 0, stream>>>(kA, fc1_w1, fc1_b1, fc1_w2, fc1_b2,
                                    fc2_w1, fc2_b1, fc2_w2, fc2_b2, w1b, w2b);
    hipMemcpyAsync(xb, x0, (size_t)NB*NN*sizeof(float), hipMemcpyDeviceToDevice, stream);

    int t1 = NB*MIDc*5*5;
    k_ctrans<<<(t1+255)/256, 256, 0, stream>>>(kA, ct1_w, ct1_b, c1, 1, MIDc, 3, 5, 2, 1, t1, 1);
    k_ct32b<5> <<<NB*2, 256, 0, stream>>>(c1, wT2, ct2_b, c2);
    k_ct32b<9> <<<NB*2, 256, 0, stream>>>(c2, wT3, ct3_b, c3);
    k_ct32b<17><<<NB*2, 256, 0, stream>>>(c3, wT4, ct4_b, c4);
    k_ct5<<<(NB*NN+255)/256, 256, 0, stream>>>(c4, wT5, ct5_b, c5);

    k_buildv<<<(NB*NN+255)/256, 256, 0, stream>>>(c5, vr, vi, NB*NN);

    for (int it = 0; it < 5; it++){
        k_smoother<<<NB, 512, 0, stream>>>(f, kA, w1b, w2b, xb);
        k_residual<<<(NB*NN+255)/256, 256, 0, stream>>>(xb, f, kA, rb);
        k_hcorrect<<<NB, 256, 0, stream>>>(Fr, Fi, rb, vr, vi, xb);
    }
    k_residual<<<(NB*NN+255)/256, 256, 0, stream>>>(xb, f, kA, rb);
    k_norm<<<256, 256, 0, stream>>>(rb, acc);
    k_final<<<1, 64, 0, stream>>>(acc, out);
}